// Round 18
// baseline (325.386 us; speedup 1.0000x reference)
//
#include <hip/hip_runtime.h>
#include <hip/hip_bf16.h>

// MultiheadAttention_ViTNO: B=8, P=256, S=8x8(=64), D=256, NHEAD=8, DK=32, SCALE=64
// R18: k2t DELETED via split-tiling k1 (one kernel, grid 1536):
//  - blocks [0,1024): Q,K with R12 tiling (full 4KB-row scores-layout stores)
//  - blocks [1024,1536): V with R16 tiling (b,sxy,pblk) + LDS-transpose
//    epilogue -> writes Vq[bn][c][q] directly in full 128B lines.
// R16 lesson: that tiling is only bad for Q/K (partial-line RMW); V path was
// correct and line-filling. R17 ledger: k1 120 plateau, k2t ~28 -> net ~-25.
// k2a(grid 256, R17 win)/k2b/k3/k0 verbatim.

typedef __bf16 bf16;
typedef __attribute__((ext_vector_type(8))) __bf16 bf16x8;
typedef __attribute__((ext_vector_type(4))) float floatx4;
typedef __attribute__((ext_vector_type(8))) unsigned short ushort8;

#define CDIM 2048             // 64*32 flattened (sxy, dk) per head

static __device__ __forceinline__ floatx4 mfma16(bf16x8 a, bf16x8 b, floatx4 c) {
  return __builtin_amdgcn_mfma_f32_16x16x32_bf16(a, b, c, 0, 0, 0);
}

static __device__ __forceinline__ void gload_lds16(const void* g, void* l) {
  __builtin_amdgcn_global_load_lds((const __attribute__((address_space(1))) void*)g,
                                   (__attribute__((address_space(3))) void*)l, 16, 0, 0);
}

// ---------------- K0: weight prep (R17 verbatim) ----------------
__global__ __launch_bounds__(256) void k0_prep(
    const float* __restrict__ Wq, const float* __restrict__ bq,
    const float* __restrict__ Wk, const float* __restrict__ bk,
    const float* __restrict__ Wv, const float* __restrict__ bv,
    const float* __restrict__ Wo,
    bf16* __restrict__ Wp, bf16* __restrict__ Wk3, float* __restrict__ biasp)
{
  const int bid = blockIdx.x, tid = threadIdx.x;
  int g = (bid & 31) * 256 + tid;       // 0..8191 : (kk, rowblk, lane)
  int lane = g & 63, rowblk = (g >> 6) & 15, kk = g >> 10;
  int h = lane >> 4, cl = lane & 15;
  int d0 = kk * 32 + 8 * h;
  if (bid < 32) {
    int ip = rowblk * 16 + cl;          // i' = n*32+dk
    int isrc = ((ip & 31) << 3) | (ip >> 5);
#pragma unroll
    for (int mat = 0; mat < 3; mat++) {
      const float* W = (mat == 0) ? Wq : (mat == 1) ? Wk : Wv;
      bf16x8 v;
#pragma unroll
      for (int j = 0; j < 8; j++) v[j] = (bf16)W[isrc * 256 + d0 + j];
      *reinterpret_cast<bf16x8*>(Wp + ((size_t)mat * 8192 + g) * 8) = v;
    }
    if (bid == 0 && tid < 256) {
      int bs = ((tid & 31) << 3) | (tid >> 5);
      biasp[tid] = bq[bs]; biasp[256 + tid] = bk[bs]; biasp[512 + tid] = bv[bs];
    }
  } else {
    int j = rowblk * 16 + cl;           // output col
    bf16x8 v;
#pragma unroll
    for (int jj = 0; jj < 8; jj++) {
      int c = d0 + jj;
      v[jj] = (bf16)Wo[j * 256 + (((c & 31) << 3) | (c >> 5))];
    }
    *reinterpret_cast<bf16x8*>(Wk3 + (size_t)g * 8) = v;
  }
}

// ---------------- K1: split-tiling fused QKV ----------------
// grid 1536; block 512 (8 waves).
// bx < 1024: Q/K path. units vb = bx + u*1024 in [0,4096):
//   a=vb>>4, mat=(vb>>3)&1, x8=vb&7, t0=(a*8+x8)*64. R12 tiling + stores.
// bx >= 1024: V path. units vb = (bx-1024) + u*512 in [0,2048):
//   b=vb>>8, sxy=(vb>>2)&63, pblk=vb&3. R16 tiling + LDS-transpose -> Vq.
__global__ __launch_bounds__(512, 4) void k1_qkv(
    const float* __restrict__ x, const bf16* __restrict__ Wp,
    const float* __restrict__ biasp,
    bf16* __restrict__ Qs, bf16* __restrict__ Ks, bf16* __restrict__ Vq)
{
  __shared__ bf16 buf[2][64 * 256];     // 2 x 32KB, granule-XOR-swizzled
  const int bx = blockIdx.x;
  const int tid = threadIdx.x;
  const int lane = tid & 63;
  const int w = tid >> 6;               // wave 0..7
  const int h = lane >> 4, cl = lane & 15;
  const int c7 = cl & 7;

  floatx4 sreg[8];
  floatx4 acc[4][2];

// shared by both paths: regs -> bf16 -> swizzled LDS
#define K1_CVTWRITE(BUFI)                                                    \
  {                                                                          \
    _Pragma("unroll")                                                        \
    for (int k = 0; k < 4; ++k) {                                            \
      int G = k * 512 + tid;                                                 \
      int row = G >> 5;                                                      \
      bf16x8 v;                                                              \
      _Pragma("unroll")                                                      \
      for (int j = 0; j < 4; j++) {                                          \
        v[j] = (bf16)sreg[2 * k][j];                                         \
        v[4 + j] = (bf16)sreg[2 * k + 1][j];                                 \
      }                                                                      \
      int Gp = (G & ~7) | ((G ^ row) & 7);                                   \
      *reinterpret_cast<bf16x8*>(&buf[BUFI][Gp * 8]) = v;                    \
    }                                                                        \
  }

// A-fragment reads from swizzled LDS (both paths)
#define K1_AFRAG(BUFI, KK, AV)                                               \
  {                                                                          \
    _Pragma("unroll")                                                        \
    for (int mt = 0; mt < 4; mt++) {                                         \
      int rr = mt * 16 + cl;                                                 \
      int G = rr * 32 + (KK) * 4 + h;                                        \
      int Gp = (G & ~7) | ((G ^ c7) & 7);                                    \
      AV[mt] = *reinterpret_cast<const bf16x8*>(&buf[BUFI][Gp * 8]);         \
    }                                                                        \
  }

  if (bx < 1024) {
    // ================= Q/K path (R12 tiling) =================
#define KQK_DEC(VB)                                                          \
    int a_ = (VB) >> 4;                                                      \
    int mat_ = ((VB) >> 3) & 1;                                              \
    int t0_ = (a_ * 8 + ((VB) & 7)) * 64;

#define KQK_LOAD(VB)                                                         \
  {                                                                          \
    KQK_DEC(VB)                                                              \
    (void)mat_;                                                              \
    _Pragma("unroll")                                                        \
    for (int k = 0; k < 4; ++k) {                                            \
      int G = k * 512 + tid;                                                 \
      int row = G >> 5;                                                      \
      const float* sp = x + (size_t)(t0_ + row) * 256 + (G & 31) * 8;        \
      sreg[2 * k]     = *reinterpret_cast<const floatx4*>(sp);               \
      sreg[2 * k + 1] = *reinterpret_cast<const floatx4*>(sp + 4);           \
    }                                                                        \
  }

#define KQK_COMPUTE(VB, BUFI)                                                \
  {                                                                          \
    KQK_DEC(VB)                                                              \
    const bf16* Wm = Wp + (size_t)mat_ * 65536;                              \
    _Pragma("unroll")                                                        \
    for (int i = 0; i < 4; i++)                                              \
      _Pragma("unroll")                                                      \
      for (int j = 0; j < 2; j++) acc[i][j] = (floatx4)0.0f;                 \
    _Pragma("unroll 2")                                                      \
    for (int kk = 0; kk < 8; ++kk) {                                         \
      bf16x8 av[4];                                                          \
      K1_AFRAG(BUFI, kk, av)                                                 \
      bf16x8 b0 = *reinterpret_cast<const bf16x8*>(                          \
          Wm + ((size_t)(kk * 16 + w * 2 + 0) * 64 + lane) * 8);             \
      bf16x8 b1 = *reinterpret_cast<const bf16x8*>(                          \
          Wm + ((size_t)(kk * 16 + w * 2 + 1) * 64 + lane) * 8);             \
      _Pragma("unroll")                                                      \
      for (int mt = 0; mt < 4; mt++) acc[mt][0] = mfma16(av[mt], b0, acc[mt][0]); \
      _Pragma("unroll")                                                      \
      for (int mt = 0; mt < 4; mt++) acc[mt][1] = mfma16(av[mt], b1, acc[mt][1]); \
    }                                                                        \
    int b_ = t0_ >> 14;                                                      \
    int p_ = (t0_ >> 6) & 255;                                               \
    bf16* ob = ((mat_ == 0) ? Qs : Ks) + ((size_t)(b_ * 8 + w) * 256 + p_) * 2048; \
    _Pragma("unroll")                                                        \
    for (int nt = 0; nt < 2; nt++) {                                         \
      const int ip = w * 32 + nt * 16 + cl;                                  \
      const float bb = biasp[mat_ * 256 + ip];                               \
      const int dk = nt * 16 + cl;                                           \
      _Pragma("unroll")                                                      \
      for (int mt = 0; mt < 4; mt++)                                         \
        _Pragma("unroll")                                                    \
        for (int r = 0; r < 4; r++) {                                        \
          int sxy = mt * 16 + 4 * h + r;                                     \
          ob[sxy * 32 + dk] = (bf16)(acc[mt][nt][r] + bb);                   \
        }                                                                    \
    }                                                                        \
  }

    KQK_LOAD(bx);
    K1_CVTWRITE(0);
    __syncthreads();
#pragma unroll
    for (int u = 1; u < 4; ++u) {
      KQK_LOAD(bx + u * 1024);
      KQK_COMPUTE(bx + (u - 1) * 1024, (u - 1) & 1);
      __syncthreads();
      K1_CVTWRITE(u & 1);
      __syncthreads();
    }
    KQK_COMPUTE(bx + 3 * 1024, 1);
#undef KQK_DEC
#undef KQK_LOAD
#undef KQK_COMPUTE
  } else {
    // ================= V path (R16 tiling + transpose epilogue) =============
    const int bxv = bx - 1024;
#define KV_DEC(VB)                                                           \
    int b_ = (VB) >> 8;                                                      \
    int sxy_ = ((VB) >> 2) & 63;                                             \
    int pblk_ = (VB) & 3;

#define KV_LOAD(VB)                                                          \
  {                                                                          \
    KV_DEC(VB)                                                               \
    _Pragma("unroll")                                                        \
    for (int k = 0; k < 4; ++k) {                                            \
      int G = k * 512 + tid;                                                 \
      int row = G >> 5;                                                      \
      const float* sp = x +                                                  \
          (size_t)((b_ * 256 + pblk_ * 64 + row) * 64 + sxy_) * 256 + (G & 31) * 8; \
      sreg[2 * k]     = *reinterpret_cast<const floatx4*>(sp);               \
      sreg[2 * k + 1] = *reinterpret_cast<const floatx4*>(sp + 4);           \
    }                                                                        \
  }

#define KV_COMPUTE(BUFI)                                                     \
  {                                                                          \
    const bf16* Wm = Wp + (size_t)2 * 65536;                                 \
    _Pragma("unroll")                                                        \
    for (int i = 0; i < 4; i++)                                              \
      _Pragma("unroll")                                                      \
      for (int j = 0; j < 2; j++) acc[i][j] = (floatx4)0.0f;                 \
    _Pragma("unroll 2")                                                      \
    for (int kk = 0; kk < 8; ++kk) {                                         \
      bf16x8 av[4];                                                          \
      K1_AFRAG(BUFI, kk, av)                                                 \
      bf16x8 b0 = *reinterpret_cast<const bf16x8*>(                          \
          Wm + ((size_t)(kk * 16 + w * 2 + 0) * 64 + lane) * 8);             \
      bf16x8 b1 = *reinterpret_cast<const bf16x8*>(                          \
          Wm + ((size_t)(kk * 16 + w * 2 + 1) * 64 + lane) * 8);             \
      _Pragma("unroll")                                                      \
      for (int mt = 0; mt < 4; mt++) acc[mt][0] = mfma16(av[mt], b0, acc[mt][0]); \
      _Pragma("unroll")                                                      \
      for (int mt = 0; mt < 4; mt++) acc[mt][1] = mfma16(av[mt], b1, acc[mt][1]); \
    }                                                                        \
  }

// acc(+bias) -> LDS transposed [ip][pl], XOR pl^(8*(ip&7))  (R16-proven)
#define KV_EPI_LDS(BUFI)                                                     \
  {                                                                          \
    _Pragma("unroll")                                                        \
    for (int nt = 0; nt < 2; nt++) {                                         \
      const int ip = w * 32 + nt * 16 + cl;                                  \
      const float bb = biasp[512 + ip];                                      \
      const int sx = 8 * (ip & 7);                                           \
      _Pragma("unroll")                                                      \
      for (int mt = 0; mt < 4; mt++)                                         \
        _Pragma("unroll")                                                    \
        for (int r = 0; r < 4; r++) {                                        \
          int pl = mt * 16 + 4 * h + r;                                      \
          buf[BUFI][ip * 64 + (pl ^ sx)] = (bf16)(acc[mt][nt][r] + bb);      \
        }                                                                    \
    }                                                                        \
  }

// LDS -> Vq[bn][c=sxy*32+dk][q=pblk*64+pl], 16B/thread, full 128B lines
#define KV_EPI_STORE(VB, BUFI)                                               \
  {                                                                          \
    KV_DEC(VB)                                                               \
    _Pragma("unroll")                                                        \
    for (int j = 0; j < 4; ++j) {                                            \
      int ip_ = j * 64 + (tid >> 3);                                         \
      int c8 = tid & 7;                                                      \
      int pb = c8 ^ (ip_ & 7);                                               \
      ushort8 v = *reinterpret_cast<const ushort8*>(                         \
          &buf[BUFI][ip_ * 64 + pb * 8]);                                    \
      int n_ = ip_ >> 5, dk_ = ip_ & 31;                                     \
      *reinterpret_cast<ushort8*>(Vq + (size_t)(b_ * 8 + n_) * 524288        \
          + (size_t)(sxy_ * 32 + dk_) * 256 + pblk_ * 64 + c8 * 8) = v;      \
    }                                                                        \
  }

    KV_LOAD(bxv);
    K1_CVTWRITE(0);
    __syncthreads();
#pragma unroll
    for (int u = 1; u < 4; ++u) {
      KV_LOAD(bxv + u * 512);
      KV_COMPUTE((u - 1) & 1);
      __syncthreads();                  // buf[(u-1)&1] reads done
      KV_EPI_LDS((u - 1) & 1);
      K1_CVTWRITE(u & 1);               // other buffer
      __syncthreads();                  // epi tile + next tile published
      KV_EPI_STORE(bxv + (u - 1) * 512, (u - 1) & 1);
    }
    KV_COMPUTE(1);
    __syncthreads();
    KV_EPI_LDS(1);
    __syncthreads();
    KV_EPI_STORE(bxv + 3 * 512, 1);
#undef KV_DEC
#undef KV_LOAD
#undef KV_COMPUTE
#undef KV_EPI_LDS
#undef KV_EPI_STORE
  }
#undef K1_CVTWRITE
#undef K1_AFRAG
}

// ---------------- K2a: scores + softmax (grid 256, R17 verbatim) ----------------
__global__ __launch_bounds__(1024, 1) void k2a_scores(
    const bf16* __restrict__ Qs, const bf16* __restrict__ Ks,
    bf16* __restrict__ attn)
{
  __shared__ bf16 Qch[2][64 * 64];      // 8KB x2
  __shared__ bf16 Kch[2][256 * 64];     // 32KB x2  (80KB total)
  __shared__ float redmax[4][4][16];
  __shared__ float redsum[4][4][16];

  const int bx = blockIdx.x;
  const int bn = bx & 63;
  const int p0 = (bx >> 6) * 64;
  const int tid = threadIdx.x;
  const int lane = tid & 63;
  const int w = tid >> 6;               // 0..15
  const int wr = w >> 2, wc = w & 3;
  const int h = lane >> 4, cl = lane & 15;

  const bf16* Qb = Qs + (size_t)bn * 524288 + (size_t)p0 * 2048;
  const bf16* Kb = Ks + (size_t)bn * 524288;

  const int rq = tid >> 3, sq = (tid & 7) ^ (rq & 7);
  const size_t qsrc = (size_t)rq * 2048 + sq * 8;
  int rk[2]; size_t ksrc[2];
#pragma unroll
  for (int i = 0; i < 2; ++i) {
    int L = i * 1024 + tid;
    rk[i] = L >> 3;
    int s = (L & 7) ^ (rk[i] & 7);
    ksrc[i] = (size_t)rk[i] * 2048 + s * 8;
  }

#define K2A_STAGE(bufi, c)                                                  \
  {                                                                         \
    if (tid < 512) gload_lds16(Qb + qsrc + (c) * 64, &Qch[bufi][(w * 64) * 8]); \
    gload_lds16(Kb + ksrc[0] + (c) * 64, &Kch[bufi][(w * 64) * 8]);         \
    gload_lds16(Kb + ksrc[1] + (c) * 64, &Kch[bufi][(1024 + w * 64) * 8]);  \
  }

  floatx4 acc[4];                       // [nt]; wave rows = wr*16 + 4h + r
#pragma unroll
  for (int j = 0; j < 4; j++) acc[j] = (floatx4)0.0f;

  K2A_STAGE(0, 0);
  __syncthreads();
  int buf = 0;
  for (int c = 0; c < 32; ++c) {
    if (c + 1 < 32) K2A_STAGE(buf ^ 1, c + 1);
#pragma unroll
    for (int kk = 0; kk < 2; ++kk) {
      bf16x8 av, bv[4];
      {
        int row = wr * 16 + cl;
        int gg = kk * 4 + h;
        av = *reinterpret_cast<const bf16x8*>(
            &Qch[buf][(row * 8 + (gg ^ (row & 7))) * 8]);
      }
#pragma unroll
      for (int nt = 0; nt < 4; nt++) {
        int row = wc * 64 + nt * 16 + cl;
        int gg = kk * 4 + h;
        bv[nt] = *reinterpret_cast<const bf16x8*>(
            &Kch[buf][(row * 8 + (gg ^ (row & 7))) * 8]);
      }
#pragma unroll
      for (int nt = 0; nt < 4; nt++) acc[nt] = mfma16(av, bv[nt], acc[nt]);
    }
    __syncthreads();
    buf ^= 1;
  }

  float pm[4];
#pragma unroll
  for (int r = 0; r < 4; r++)
    pm[r] = fmaxf(fmaxf(acc[0][r], acc[1][r]), fmaxf(acc[2][r], acc[3][r]));
#pragma unroll
  for (int off = 1; off < 16; off <<= 1)
#pragma unroll
    for (int r = 0; r < 4; r++)
      pm[r] = fmaxf(pm[r], __shfl_xor(pm[r], off, 64));
  if (cl == 0) {
#pragma unroll
    for (int r = 0; r < 4; r++) redmax[wr][wc][4 * h + r] = pm[r];
  }
  __syncthreads();

  float gm[4], ps[4];
#pragma unroll
  for (int r = 0; r < 4; r++) {
    int row = 4 * h + r;
    gm[r] = fmaxf(fmaxf(redmax[wr][0][row], redmax[wr][1][row]),
                  fmaxf(redmax[wr][2][row], redmax[wr][3][row]));
    ps[r] = 0.0f;
  }
  const float KS = 1.44269504088896340736f / 64.0f;   // log2(e)/SCALE
#pragma unroll
  for (int nt = 0; nt < 4; nt++)
#pragma unroll
    for (int r = 0; r < 4; r++) {
      float e = exp2f((acc[nt][r] - gm[r]) * KS);
      acc[nt][r] = e;
      ps[r] += e;
    }
#pragma unroll
  for (int off = 1; off < 16; off <<= 1)
#pragma unroll
    for (int r = 0; r < 4; r++) ps[r] += __shfl_xor(ps[r], off, 64);
  if (cl == 0) {
#pragma unroll
    for (int r = 0; r < 4; r++) redsum[wr][wc][4 * h + r] = ps[r];
  }
  __syncthreads();

#pragma unroll
  for (int r = 0; r < 4; r++) {
    int row = 4 * h + r;
    float gs = (redsum[wr][0][row] + redsum[wr][1][row])
             + (redsum[wr][2][row] + redsum[wr][3][row]);
    ps[r] = 1.0f / gs;
  }
#pragma unroll
  for (int nt = 0; nt < 4; nt++) {
    int q = wc * 64 + nt * 16 + cl;
#pragma unroll
    for (int r = 0; r < 4; r++) {
      int row = p0 + wr * 16 + 4 * h + r;
      attn[(size_t)bn * 65536 + row * 256 + q] = (bf16)(acc[nt][r] * ps[r]);
    }
  }
#undef K2A_STAGE
}

// ---------------- K2b: O = attn @ V (R17 verbatim) ----------------
__global__ __launch_bounds__(512, 6) void k2b_pv(
    const bf16* __restrict__ attn, const bf16* __restrict__ Vq,
    bf16* __restrict__ yhat)
{
  __shared__ bf16 As[64 * 256];         // 32KB
  const int bx = blockIdx.x;
  const int bn = bx & 63;
  const int r2 = bx >> 6;               // 0..31
  const int p0 = (r2 & 3) * 64;
  const int c0 = (r2 >> 2) * 256;
  const int b = bn >> 3, n = bn & 7;
  const int tid = threadIdx.x;
  const int lane = tid & 63;
  const int w = tid >> 6;               // wave -> 32-c slice of ctile
  const int h = lane >> 4, cl = lane & 15;
  const int c7 = cl & 7;

  const bf16* Ab = attn + (size_t)bn * 65536 + (size_t)p0 * 256;
  const bf16* Vb = Vq + (size_t)bn * 524288;

#pragma unroll
  for (int i = 0; i < 4; ++i) {
    int L = (i * 8 + w) * 64 + lane;
    int S = (L & ~7) | ((L ^ (L >> 5)) & 7);
    gload_lds16(Ab + (size_t)S * 8, &As[(size_t)(i * 8 + w) * 64 * 8]);
  }
  __syncthreads();

  floatx4 acc[4][2];
#pragma unroll
  for (int i = 0; i < 4; i++)
#pragma unroll
    for (int j = 0; j < 2; j++) acc[i][j] = (floatx4)0.0f;

#pragma unroll 2
  for (int kk = 0; kk < 8; ++kk) {
    bf16x8 av[4];
#pragma unroll
    for (int mt = 0; mt < 4; mt++) {
      int rr = mt * 16 + cl;
      int G = rr * 32 + kk * 4 + h;
      int Gp = (G & ~7) | ((G ^ c7) & 7);
      av[mt] = *reinterpret_cast<const bf16x8*>(&As[Gp * 8]);
    }
    bf16x8 b0 = *reinterpret_cast<const bf16x8*>(
        Vb + (size_t)(c0 + w * 32 + cl) * 256 + kk * 32 + 8 * h);
    bf16x8 b1 = *reinterpret_cast<const bf16x8*>(
        Vb + (size_t)(c0 + w * 32 + 16 + cl) * 256 + kk * 32 + 8 * h);
#pragma unroll
    for (int mt = 0; mt < 4; mt++) acc[mt][0] = mfma16(av[mt], b0, acc[mt][0]);
#pragma unroll
    for (int mt = 0; mt < 4; mt++) acc[mt][1] = mfma16(av[mt], b1, acc[mt][1]);
  }

#pragma unroll
  for (int nt = 0; nt < 2; nt++) {
    const int cg = c0 + w * 32 + nt * 16 + cl;
    const int dk = cg & 31, sxy = cg >> 5;
#pragma unroll
    for (int mt = 0; mt < 4; mt++)
#pragma unroll
      for (int r = 0; r < 4; r++) {
        int p = p0 + mt * 16 + 4 * h + r;
        size_t t = (size_t)((b * 256 + p) * 64) + sxy;
        yhat[t * 256 + n * 32 + dk] = (bf16)acc[mt][nt][r];
      }
  }
}

// ---------------- K3: output projection (R17 verbatim) ----------------
__global__ __launch_bounds__(512, 6) void k3_out(
    const bf16* __restrict__ yhat, const bf16* __restrict__ Wk3,
    const float* __restrict__ bo, float* __restrict__ outp)
{
  __shared__ bf16 As[64 * 256];         // 32KB
  const int t0 = blockIdx.x * 64;
  const int tid = threadIdx.x;
  const int lane = tid & 63;
  const int w = tid >> 6;
  const int h = lane >> 4, cl = lane & 15;
  const int c7 = cl & 7;

  const bf16* Ab = yhat + (size_t)t0 * 256;

#pragma unroll
  for (int i = 0; i < 4; ++i) {
    int L = (i * 8 + w) * 64 + lane;
    int S = (L & ~7) | ((L ^ (L >> 5)) & 7);
    gload_lds16(Ab + (size_t)S * 8, &As[(size_t)(i * 8 + w) * 64 * 8]);
  }
  __syncthreads();

  floatx4 acc[4][2];
#pragma unroll
  for (int i = 0; i < 4; i++)
#pragma unroll
    for (int j = 0; j < 2; j++) acc[i][j] = (floatx4)0.0f;

#pragma unroll 2
  for (int kk = 0; kk < 8; ++kk) {
    bf16x8 av[4];
#pragma unroll
    for (int mt = 0; mt < 4; mt++) {
      int rr = mt * 16 + cl;
      int G = rr * 32 + kk * 4 + h;
      int Gp = (G & ~7) | ((G ^ c7) & 7);
      av[mt] = *reinterpret_cast<const bf16x8*>(&As[Gp * 8]);
    }
    bf16x8 b0 = *reinterpret_cast<const bf16x8*>(
        Wk3 + ((size_t)(kk * 16 + w * 2 + 0) * 64 + lane) * 8);
    bf16x8 b1 = *reinterpret_cast<const bf16x8*>(
        Wk3 + ((size_t)(kk * 16 + w * 2 + 1) * 64 + lane) * 8);
#pragma unroll
    for (int mt = 0; mt < 4; mt++) acc[mt][0] = mfma16(av[mt], b0, acc[mt][0]);
#pragma unroll
    for (int mt = 0; mt < 4; mt++) acc[mt][1] = mfma16(av[mt], b1, acc[mt][1]);
  }

#pragma unroll
  for (int nt = 0; nt < 2; nt++) {
    const int j = w * 32 + nt * 16 + cl;
    const float bb = bo[j];
#pragma unroll
    for (int mt = 0; mt < 4; mt++)
#pragma unroll
      for (int r = 0; r < 4; r++)
        outp[(size_t)(t0 + mt * 16 + 4 * h + r) * 256 + j] = acc[mt][nt][r] + bb;
  }
}

// ---------------- launch ----------------
extern "C" void kernel_launch(void* const* d_in, const int* in_sizes, int n_in,
                              void* d_out, int out_size, void* d_ws, size_t ws_size,
                              hipStream_t stream) {
  const float* x  = (const float*)d_in[0];
  const float* Wq = (const float*)d_in[1];
  const float* bq = (const float*)d_in[2];
  const float* Wk = (const float*)d_in[3];
  const float* bk = (const float*)d_in[4];
  const float* Wv = (const float*)d_in[5];
  const float* bv = (const float*)d_in[6];
  const float* Wo = (const float*)d_in[7];
  const float* bo = (const float*)d_in[8];
  float* outp = (float*)d_out;

  char* ws = (char*)d_ws;
  const size_t SZ_QKV = 67108864;   // 64*256*2048 * 2B
  size_t off = 0;
  bf16* Qs   = (bf16*)(ws + off); off += SZ_QKV;
  bf16* Ks   = (bf16*)(ws + off); off += SZ_QKV;
  bf16* Vq   = (bf16*)(ws + off); off += SZ_QKV;   // k1 writes Vq directly
  bf16* attn = (bf16*)(ws + off); off += 8388608;
  bf16* Wp   = (bf16*)(ws + off); off += 393216;   // qkv fragment packs
  bf16* Wk3  = (bf16*)(ws + off); off += 131072;   // k3 fragment pack
  float* biasp = (float*)(ws + off); off += 3072;
  if (ws_size < off) return;        // workspace too small: bail cleanly

  bf16* yhat = Qs;                  // Qs dead after k2a

  k0_prep<<<64, 256, 0, stream>>>(Wq, bq, Wk, bk, Wv, bv, Wo, Wp, Wk3, biasp);
  k1_qkv<<<1536, 512, 0, stream>>>(x, Wp, biasp, Qs, Ks, Vq);
  k2a_scores<<<256, 1024, 0, stream>>>(Qs, Ks, attn);
  k2b_pv<<<2048, 512, 0, stream>>>(attn, Vq, yhat);
  k3_out<<<2048, 512, 0, stream>>>(yhat, Wk3, bo, outp);
}

// Round 19
// 303.759 us; speedup vs baseline: 1.0712x; 1.0712x over previous
//
#include <hip/hip_runtime.h>
#include <hip/hip_bf16.h>

// MultiheadAttention_ViTNO: B=8, P=256, S=8x8(=64), D=256, NHEAD=8, DK=32, SCALE=64
// R19: revert to R17 (298us best; R18's split-k1 thrashed L3: FETCH 69->176MB).
// ONE change: k2a (grid 256) gets R12's proven counted-vmcnt triple-buffer:
// STAGE(c+2); compute(c); per-wave vmcnt(3|2) (waves 0-7 stage 3 loads/chunk,
// 8-15 stage 2); raw s_barrier. At 1 block/CU there is no cross-block overlap,
// so in-block pipelining is the only cover for the per-chunk vmcnt(0) drain.
// k0/k1/k2t/k2b/k3 = R17 verbatim.

typedef __bf16 bf16;
typedef __attribute__((ext_vector_type(8))) __bf16 bf16x8;
typedef __attribute__((ext_vector_type(4))) float floatx4;
typedef __attribute__((ext_vector_type(8))) unsigned short ushort8;

#define CDIM 2048             // 64*32 flattened (sxy, dk) per head

static __device__ __forceinline__ floatx4 mfma16(bf16x8 a, bf16x8 b, floatx4 c) {
  return __builtin_amdgcn_mfma_f32_16x16x32_bf16(a, b, c, 0, 0, 0);
}

static __device__ __forceinline__ void gload_lds16(const void* g, void* l) {
  __builtin_amdgcn_global_load_lds((const __attribute__((address_space(1))) void*)g,
                                   (__attribute__((address_space(3))) void*)l, 16, 0, 0);
}

// ---------------- K0: weight prep (R17 verbatim) ----------------
__global__ __launch_bounds__(256) void k0_prep(
    const float* __restrict__ Wq, const float* __restrict__ bq,
    const float* __restrict__ Wk, const float* __restrict__ bk,
    const float* __restrict__ Wv, const float* __restrict__ bv,
    const float* __restrict__ Wo,
    bf16* __restrict__ Wp, bf16* __restrict__ Wk3, float* __restrict__ biasp)
{
  const int bid = blockIdx.x, tid = threadIdx.x;
  int g = (bid & 31) * 256 + tid;       // 0..8191 : (kk, rowblk, lane)
  int lane = g & 63, rowblk = (g >> 6) & 15, kk = g >> 10;
  int h = lane >> 4, cl = lane & 15;
  int d0 = kk * 32 + 8 * h;
  if (bid < 32) {
    int ip = rowblk * 16 + cl;          // i' = n*32+dk
    int isrc = ((ip & 31) << 3) | (ip >> 5);
#pragma unroll
    for (int mat = 0; mat < 3; mat++) {
      const float* W = (mat == 0) ? Wq : (mat == 1) ? Wk : Wv;
      bf16x8 v;
#pragma unroll
      for (int j = 0; j < 8; j++) v[j] = (bf16)W[isrc * 256 + d0 + j];
      *reinterpret_cast<bf16x8*>(Wp + ((size_t)mat * 8192 + g) * 8) = v;
    }
    if (bid == 0 && tid < 256) {
      int bs = ((tid & 31) << 3) | (tid >> 5);
      biasp[tid] = bq[bs]; biasp[256 + tid] = bk[bs]; biasp[512 + tid] = bv[bs];
    }
  } else {
    int j = rowblk * 16 + cl;           // output col
    bf16x8 v;
#pragma unroll
    for (int jj = 0; jj < 8; jj++) {
      int c = d0 + jj;
      v[jj] = (bf16)Wo[j * 256 + (((c & 31) << 3) | (c >> 5))];
    }
    *reinterpret_cast<bf16x8*>(Wk3 + (size_t)g * 8) = v;
  }
}

// ---------------- K1: fused QKV projection, pipelined persistent (R17) ----------
__global__ __launch_bounds__(512, 4) void k1_qkv(
    const float* __restrict__ x, const bf16* __restrict__ Wp,
    const float* __restrict__ biasp,
    bf16* __restrict__ Qs, bf16* __restrict__ Ks, bf16* __restrict__ Vt)
{
  __shared__ bf16 buf[2][64 * 256];     // 2 x 32KB, granule-XOR-swizzled
  const int bx = blockIdx.x;
  const int tid = threadIdx.x;
  const int lane = tid & 63;
  const int w = tid >> 6;               // wave 0..7 -> ip slice [w*32, w*32+32)
  const int h = lane >> 4, cl = lane & 15;
  const int c7 = cl & 7;

  floatx4 sreg[8];                      // 32 VGPR staging (one 64-token tile)

#define K1_LOAD(VB)                                                          \
  {                                                                          \
    int a_ = (VB) / 24;                                                      \
    int t0_ = (a_ * 8 + ((VB) & 7)) * 64;                                    \
    _Pragma("unroll")                                                        \
    for (int k = 0; k < 4; ++k) {                                            \
      int G = k * 512 + tid;                                                 \
      int row = G >> 5;                                                      \
      const float* sp = x + (size_t)(t0_ + row) * 256 + (G & 31) * 8;        \
      sreg[2 * k]     = *reinterpret_cast<const floatx4*>(sp);               \
      sreg[2 * k + 1] = *reinterpret_cast<const floatx4*>(sp + 4);           \
    }                                                                        \
  }

#define K1_CVTWRITE(BUFI)                                                    \
  {                                                                          \
    _Pragma("unroll")                                                        \
    for (int k = 0; k < 4; ++k) {                                            \
      int G = k * 512 + tid;                                                 \
      int row = G >> 5;                                                      \
      bf16x8 v;                                                              \
      _Pragma("unroll")                                                      \
      for (int j = 0; j < 4; j++) {                                          \
        v[j] = (bf16)sreg[2 * k][j];                                         \
        v[4 + j] = (bf16)sreg[2 * k + 1][j];                                 \
      }                                                                      \
      int Gp = (G & ~7) | ((G ^ row) & 7);                                   \
      *reinterpret_cast<bf16x8*>(&buf[BUFI][Gp * 8]) = v;                    \
    }                                                                        \
  }

#define K1_COMPUTE(VB, BUFI)                                                 \
  {                                                                          \
    int a_ = (VB) / 24;                                                      \
    int rem_ = (VB) - a_ * 24;                                               \
    int mat_ = rem_ >> 3;                                                    \
    int t0_ = (a_ * 8 + (rem_ & 7)) * 64;                                    \
    const bf16* Wm = Wp + (size_t)mat_ * 65536;                              \
    floatx4 acc[4][2];                                                       \
    _Pragma("unroll")                                                        \
    for (int i = 0; i < 4; i++)                                              \
      _Pragma("unroll")                                                      \
      for (int j = 0; j < 2; j++) acc[i][j] = (floatx4)0.0f;                 \
    _Pragma("unroll 2")                                                      \
    for (int kk = 0; kk < 8; ++kk) {                                         \
      bf16x8 av[4];                                                          \
      _Pragma("unroll")                                                      \
      for (int mt = 0; mt < 4; mt++) {                                       \
        int rr = mt * 16 + cl;                                               \
        int G = rr * 32 + kk * 4 + h;                                        \
        int Gp = (G & ~7) | ((G ^ c7) & 7);                                  \
        av[mt] = *reinterpret_cast<const bf16x8*>(&buf[BUFI][Gp * 8]);       \
      }                                                                      \
      bf16x8 b0 = *reinterpret_cast<const bf16x8*>(                          \
          Wm + ((size_t)(kk * 16 + w * 2 + 0) * 64 + lane) * 8);             \
      bf16x8 b1 = *reinterpret_cast<const bf16x8*>(                          \
          Wm + ((size_t)(kk * 16 + w * 2 + 1) * 64 + lane) * 8);             \
      _Pragma("unroll")                                                      \
      for (int mt = 0; mt < 4; mt++) acc[mt][0] = mfma16(av[mt], b0, acc[mt][0]); \
      _Pragma("unroll")                                                      \
      for (int mt = 0; mt < 4; mt++) acc[mt][1] = mfma16(av[mt], b1, acc[mt][1]); \
    }                                                                        \
    int b_ = t0_ >> 14;                                                      \
    int p_ = (t0_ >> 6) & 255;                                               \
    if (mat_ < 2) {                                                          \
      bf16* ob = ((mat_ == 0) ? Qs : Ks) + ((size_t)(b_ * 8 + w) * 256 + p_) * 2048; \
      _Pragma("unroll")                                                      \
      for (int nt = 0; nt < 2; nt++) {                                       \
        const int ip = w * 32 + nt * 16 + cl;                                \
        const float bb = biasp[mat_ * 256 + ip];                             \
        const int dk = nt * 16 + cl;                                         \
        _Pragma("unroll")                                                    \
        for (int mt = 0; mt < 4; mt++)                                       \
          _Pragma("unroll")                                                  \
          for (int r = 0; r < 4; r++) {                                      \
            int sxy = mt * 16 + 4 * h + r;                                   \
            ob[sxy * 32 + dk] = (bf16)(acc[mt][nt][r] + bb);                 \
          }                                                                  \
      }                                                                      \
    } else {                                                                 \
      _Pragma("unroll")                                                      \
      for (int nt = 0; nt < 2; nt++) {                                       \
        const int ip = w * 32 + nt * 16 + cl;                                \
        const float bb = biasp[512 + ip];                                    \
        _Pragma("unroll")                                                    \
        for (int mt = 0; mt < 4; mt++)                                       \
          _Pragma("unroll")                                                  \
          for (int r = 0; r < 4; r++) {                                      \
            int t = t0_ + mt * 16 + 4 * h + r;                               \
            Vt[(size_t)t * 256 + ip] = (bf16)(acc[mt][nt][r] + bb);          \
          }                                                                  \
      }                                                                      \
    }                                                                        \
  }

  K1_LOAD(bx);
  K1_CVTWRITE(0);
  __syncthreads();
#pragma unroll
  for (int u = 1; u < 4; ++u) {
    K1_LOAD(bx + u * 1536);
    K1_COMPUTE(bx + (u - 1) * 1536, (u - 1) & 1);
    __syncthreads();
    K1_CVTWRITE(u & 1);
    __syncthreads();
  }
  K1_COMPUTE(bx + 3 * 1536, 1);

#undef K1_LOAD
#undef K1_CVTWRITE
#undef K1_COMPUTE
}

// ---------------- K2a: scores + softmax (grid 256, counted-vmcnt 3-buffer) ----
// grid 256 = 64 bn (low bits) x 4 p-quarters of 64; block 1024 (16 waves,
// wr=p-slice 16 rows, wc=q-slice 64). Triple buffer, 2-chunk-ahead prefetch;
// waves 0-7 stage 3 loads/chunk (Q+2K) -> vmcnt(3); waves 8-15 stage 2 -> vmcnt(2).
__global__ __launch_bounds__(1024, 1) void k2a_scores(
    const bf16* __restrict__ Qs, const bf16* __restrict__ Ks,
    bf16* __restrict__ attn)
{
  __shared__ bf16 Qch[3][64 * 64];      // 8KB x3
  __shared__ bf16 Kch[3][256 * 64];     // 32KB x3  (120KB total)
  __shared__ float redmax[4][4][16];
  __shared__ float redsum[4][4][16];

  const int bx = blockIdx.x;
  const int bn = bx & 63;
  const int p0 = (bx >> 6) * 64;
  const int tid = threadIdx.x;
  const int lane = tid & 63;
  const int w = tid >> 6;               // 0..15
  const int wr = w >> 2, wc = w & 3;
  const int h = lane >> 4, cl = lane & 15;

  const bf16* Qb = Qs + (size_t)bn * 524288 + (size_t)p0 * 2048;
  const bf16* Kb = Ks + (size_t)bn * 524288;

  // Q: 512 granules (64 rows x 8), staged by waves 0..7 (1 granule/thread)
  const int rq = tid >> 3, sq = (tid & 7) ^ (rq & 7);
  const size_t qsrc = (size_t)rq * 2048 + sq * 8;
  // K: 2048 granules, 2/thread
  int rk[2]; size_t ksrc[2];
#pragma unroll
  for (int i = 0; i < 2; ++i) {
    int L = i * 1024 + tid;
    rk[i] = L >> 3;
    int s = (L & 7) ^ (rk[i] & 7);
    ksrc[i] = (size_t)rk[i] * 2048 + s * 8;
  }

#define K2A_STAGE(bufi, c)                                                  \
  {                                                                         \
    if (tid < 512) gload_lds16(Qb + qsrc + (c) * 64, &Qch[bufi][(w * 64) * 8]); \
    gload_lds16(Kb + ksrc[0] + (c) * 64, &Kch[bufi][(w * 64) * 8]);         \
    gload_lds16(Kb + ksrc[1] + (c) * 64, &Kch[bufi][(1024 + w * 64) * 8]);  \
  }

// per-wave counted wait: waves 0-7 have 3 outstanding/chunk, 8-15 have 2
#define K2A_WAIT_AHEAD()                                                    \
  {                                                                         \
    if (w < 8) asm volatile("s_waitcnt vmcnt(3)" ::: "memory");             \
    else       asm volatile("s_waitcnt vmcnt(2)" ::: "memory");             \
  }

  floatx4 acc[4];                       // [nt]; wave rows = wr*16 + 4h + r
#pragma unroll
  for (int j = 0; j < 4; j++) acc[j] = (floatx4)0.0f;

  // prologue: chunks 0,1 in flight; publish chunk 0
  K2A_STAGE(0, 0);
  K2A_STAGE(1, 1);
  K2A_WAIT_AHEAD();
  __builtin_amdgcn_s_barrier();
  __builtin_amdgcn_sched_barrier(0);

  for (int c = 0; c < 32; ++c) {
    const int cur = c % 3;
    if (c + 2 < 32) { const int nb = (c + 2) % 3; K2A_STAGE(nb, c + 2); }
#pragma unroll
    for (int kk = 0; kk < 2; ++kk) {
      bf16x8 av, bv[4];
      {
        int row = wr * 16 + cl;
        int gg = kk * 4 + h;
        av = *reinterpret_cast<const bf16x8*>(
            &Qch[cur][(row * 8 + (gg ^ (row & 7))) * 8]);
      }
#pragma unroll
      for (int nt = 0; nt < 4; nt++) {
        int row = wc * 64 + nt * 16 + cl;
        int gg = kk * 4 + h;
        bv[nt] = *reinterpret_cast<const bf16x8*>(
            &Kch[cur][(row * 8 + (gg ^ (row & 7))) * 8]);
      }
#pragma unroll
      for (int nt = 0; nt < 4; nt++) acc[nt] = mfma16(av, bv[nt], acc[nt]);
    }
    if (c + 2 < 32) { K2A_WAIT_AHEAD(); }
    else            { asm volatile("s_waitcnt vmcnt(0)" ::: "memory"); }
    __builtin_amdgcn_s_barrier();
    __builtin_amdgcn_sched_barrier(0);
  }

  // softmax over q (rows local: wr*16 + 4h + r)
  float pm[4];
#pragma unroll
  for (int r = 0; r < 4; r++)
    pm[r] = fmaxf(fmaxf(acc[0][r], acc[1][r]), fmaxf(acc[2][r], acc[3][r]));
#pragma unroll
  for (int off = 1; off < 16; off <<= 1)
#pragma unroll
    for (int r = 0; r < 4; r++)
      pm[r] = fmaxf(pm[r], __shfl_xor(pm[r], off, 64));
  if (cl == 0) {
#pragma unroll
    for (int r = 0; r < 4; r++) redmax[wr][wc][4 * h + r] = pm[r];
  }
  __syncthreads();

  float gm[4], ps[4];
#pragma unroll
  for (int r = 0; r < 4; r++) {
    int row = 4 * h + r;
    gm[r] = fmaxf(fmaxf(redmax[wr][0][row], redmax[wr][1][row]),
                  fmaxf(redmax[wr][2][row], redmax[wr][3][row]));
    ps[r] = 0.0f;
  }
  const float KS = 1.44269504088896340736f / 64.0f;   // log2(e)/SCALE
#pragma unroll
  for (int nt = 0; nt < 4; nt++)
#pragma unroll
    for (int r = 0; r < 4; r++) {
      float e = exp2f((acc[nt][r] - gm[r]) * KS);
      acc[nt][r] = e;
      ps[r] += e;
    }
#pragma unroll
  for (int off = 1; off < 16; off <<= 1)
#pragma unroll
    for (int r = 0; r < 4; r++) ps[r] += __shfl_xor(ps[r], off, 64);
  if (cl == 0) {
#pragma unroll
    for (int r = 0; r < 4; r++) redsum[wr][wc][4 * h + r] = ps[r];
  }
  __syncthreads();

#pragma unroll
  for (int r = 0; r < 4; r++) {
    int row = 4 * h + r;
    float gs = (redsum[wr][0][row] + redsum[wr][1][row])
             + (redsum[wr][2][row] + redsum[wr][3][row]);
    ps[r] = 1.0f / gs;
  }
#pragma unroll
  for (int nt = 0; nt < 4; nt++) {
    int q = wc * 64 + nt * 16 + cl;
#pragma unroll
    for (int r = 0; r < 4; r++) {
      int row = p0 + wr * 16 + 4 * h + r;
      attn[(size_t)bn * 65536 + row * 256 + q] = (bf16)(acc[nt][r] * ps[r]);
    }
  }
#undef K2A_STAGE
#undef K2A_WAIT_AHEAD
}

// ---------------- K2t: V transpose (R17 verbatim) ----------------
__global__ __launch_bounds__(256) void k2t_transpose(
    const bf16* __restrict__ Vtok, bf16* __restrict__ Vq)
{
  const int bx = blockIdx.x;
  const int bn = bx & 63;
  const int r2 = bx >> 6;                  // 0..127
  const int q0 = (r2 & 3) * 64;
  const int c0 = (r2 >> 2) * 64;           // c = sxy*32 + dk
  const int b = bn >> 3, n = bn & 7;
  __shared__ unsigned short tile[64][65];
  const unsigned short* src = (const unsigned short*)Vtok;
  unsigned short* dst = (unsigned short*)Vq + (size_t)bn * 524288;
  {
    const int q = threadIdx.x >> 3;            // 0..31
    const int cj = (threadIdx.x & 7) * 8;
    const int c = c0 + cj;
    const int sxy = c >> 5, dk0 = c & 31;
#pragma unroll
    for (int it = 0; it < 2; ++it) {
      int qq = q + it * 32;
      size_t sa = (size_t)((b * 256 + q0 + qq) * 64 + sxy) * 256 + n * 32 + dk0;
      ushort8 s = *reinterpret_cast<const ushort8*>(src + sa);
#pragma unroll
      for (int j = 0; j < 8; j++) tile[qq][cj + j] = s[j];
    }
  }
  __syncthreads();
  {
    const int crow = threadIdx.x >> 2;         // 0..63
    const int qj = (threadIdx.x & 3) * 8;
#pragma unroll
    for (int it = 0; it < 2; ++it) {
      int qq = qj + it * 32;
      ushort8 sv;
#pragma unroll
      for (int j = 0; j < 8; j++) sv[j] = tile[qq + j][crow];
      *reinterpret_cast<ushort8*>(dst + (size_t)(c0 + crow) * 256 + q0 + qq) = sv;
    }
  }
}

// ---------------- K2b: O = attn @ V (R17 verbatim) ----------------
__global__ __launch_bounds__(512, 6) void k2b_pv(
    const bf16* __restrict__ attn, const bf16* __restrict__ Vq,
    bf16* __restrict__ yhat)
{
  __shared__ bf16 As[64 * 256];         // 32KB
  const int bx = blockIdx.x;
  const int bn = bx & 63;
  const int r2 = bx >> 6;               // 0..31
  const int p0 = (r2 & 3) * 64;
  const int c0 = (r2 >> 2) * 256;
  const int b = bn >> 3, n = bn & 7;
  const int tid = threadIdx.x;
  const int lane = tid & 63;
  const int w = tid >> 6;               // wave -> 32-c slice of ctile
  const int h = lane >> 4, cl = lane & 15;
  const int c7 = cl & 7;

  const bf16* Ab = attn + (size_t)bn * 65536 + (size_t)p0 * 256;
  const bf16* Vb = Vq + (size_t)bn * 524288;

#pragma unroll
  for (int i = 0; i < 4; ++i) {
    int L = (i * 8 + w) * 64 + lane;
    int S = (L & ~7) | ((L ^ (L >> 5)) & 7);
    gload_lds16(Ab + (size_t)S * 8, &As[(size_t)(i * 8 + w) * 64 * 8]);
  }
  __syncthreads();

  floatx4 acc[4][2];
#pragma unroll
  for (int i = 0; i < 4; i++)
#pragma unroll
    for (int j = 0; j < 2; j++) acc[i][j] = (floatx4)0.0f;

#pragma unroll 2
  for (int kk = 0; kk < 8; ++kk) {
    bf16x8 av[4];
#pragma unroll
    for (int mt = 0; mt < 4; mt++) {
      int rr = mt * 16 + cl;
      int G = rr * 32 + kk * 4 + h;
      int Gp = (G & ~7) | ((G ^ c7) & 7);
      av[mt] = *reinterpret_cast<const bf16x8*>(&As[Gp * 8]);
    }
    bf16x8 b0 = *reinterpret_cast<const bf16x8*>(
        Vb + (size_t)(c0 + w * 32 + cl) * 256 + kk * 32 + 8 * h);
    bf16x8 b1 = *reinterpret_cast<const bf16x8*>(
        Vb + (size_t)(c0 + w * 32 + 16 + cl) * 256 + kk * 32 + 8 * h);
#pragma unroll
    for (int mt = 0; mt < 4; mt++) acc[mt][0] = mfma16(av[mt], b0, acc[mt][0]);
#pragma unroll
    for (int mt = 0; mt < 4; mt++) acc[mt][1] = mfma16(av[mt], b1, acc[mt][1]);
  }

#pragma unroll
  for (int nt = 0; nt < 2; nt++) {
    const int cg = c0 + w * 32 + nt * 16 + cl;
    const int dk = cg & 31, sxy = cg >> 5;
#pragma unroll
    for (int mt = 0; mt < 4; mt++)
#pragma unroll
      for (int r = 0; r < 4; r++) {
        int p = p0 + mt * 16 + 4 * h + r;
        size_t t = (size_t)((b * 256 + p) * 64) + sxy;
        yhat[t * 256 + n * 32 + dk] = (bf16)acc[mt][nt][r];
      }
  }
}

// ---------------- K3: output projection (R17 verbatim) ----------------
__global__ __launch_bounds__(512, 6) void k3_out(
    const bf16* __restrict__ yhat, const bf16* __restrict__ Wk3,
    const float* __restrict__ bo, float* __restrict__ outp)
{
  __shared__ bf16 As[64 * 256];         // 32KB
  const int t0 = blockIdx.x * 64;
  const int tid = threadIdx.x;
  const int lane = tid & 63;
  const int w = tid >> 6;
  const int h = lane >> 4, cl = lane & 15;
  const int c7 = cl & 7;

  const bf16* Ab = yhat + (size_t)t0 * 256;

#pragma unroll
  for (int i = 0; i < 4; ++i) {
    int L = (i * 8 + w) * 64 + lane;
    int S = (L & ~7) | ((L ^ (L >> 5)) & 7);
    gload_lds16(Ab + (size_t)S * 8, &As[(size_t)(i * 8 + w) * 64 * 8]);
  }
  __syncthreads();

  floatx4 acc[4][2];
#pragma unroll
  for (int i = 0; i < 4; i++)
#pragma unroll
    for (int j = 0; j < 2; j++) acc[i][j] = (floatx4)0.0f;

#pragma unroll 2
  for (int kk = 0; kk < 8; ++kk) {
    bf16x8 av[4];
#pragma unroll
    for (int mt = 0; mt < 4; mt++) {
      int rr = mt * 16 + cl;
      int G = rr * 32 + kk * 4 + h;
      int Gp = (G & ~7) | ((G ^ c7) & 7);
      av[mt] = *reinterpret_cast<const bf16x8*>(&As[Gp * 8]);
    }
    bf16x8 b0 = *reinterpret_cast<const bf16x8*>(
        Wk3 + ((size_t)(kk * 16 + w * 2 + 0) * 64 + lane) * 8);
    bf16x8 b1 = *reinterpret_cast<const bf16x8*>(
        Wk3 + ((size_t)(kk * 16 + w * 2 + 1) * 64 + lane) * 8);
#pragma unroll
    for (int mt = 0; mt < 4; mt++) acc[mt][0] = mfma16(av[mt], b0, acc[mt][0]);
#pragma unroll
    for (int mt = 0; mt < 4; mt++) acc[mt][1] = mfma16(av[mt], b1, acc[mt][1]);
  }

#pragma unroll
  for (int nt = 0; nt < 2; nt++) {
    const int j = w * 32 + nt * 16 + cl;
    const float bb = bo[j];
#pragma unroll
    for (int mt = 0; mt < 4; mt++)
#pragma unroll
      for (int r = 0; r < 4; r++)
        outp[(size_t)(t0 + mt * 16 + 4 * h + r) * 256 + j] = acc[mt][nt][r] + bb;
  }
}

// ---------------- launch ----------------
extern "C" void kernel_launch(void* const* d_in, const int* in_sizes, int n_in,
                              void* d_out, int out_size, void* d_ws, size_t ws_size,
                              hipStream_t stream) {
  const float* x  = (const float*)d_in[0];
  const float* Wq = (const float*)d_in[1];
  const float* bq = (const float*)d_in[2];
  const float* Wk = (const float*)d_in[3];
  const float* bk = (const float*)d_in[4];
  const float* Wv = (const float*)d_in[5];
  const float* bv = (const float*)d_in[6];
  const float* Wo = (const float*)d_in[7];
  const float* bo = (const float*)d_in[8];
  float* outp = (float*)d_out;

  char* ws = (char*)d_ws;
  const size_t SZ_QKV = 67108864;   // 64*256*2048 * 2B
  size_t off = 0;
  bf16* Qs   = (bf16*)(ws + off); off += SZ_QKV;
  bf16* Ks   = (bf16*)(ws + off); off += SZ_QKV;
  bf16* Vtok = (bf16*)(ws + off); off += SZ_QKV;
  bf16* attn = (bf16*)(ws + off); off += 8388608;
  bf16* Wp   = (bf16*)(ws + off); off += 393216;   // qkv fragment packs
  bf16* Wk3  = (bf16*)(ws + off); off += 131072;   // k3 fragment pack
  float* biasp = (float*)(ws + off); off += 3072;
  if (ws_size < off) return;        // workspace too small: bail cleanly

  bf16* yhat = Qs;                  // Qs dead after k2a
  bf16* Vq   = Ks;                  // Ks dead after k2a (k2t runs after k2a)

  k0_prep<<<64, 256, 0, stream>>>(Wq, bq, Wk, bk, Wv, bv, Wo, Wp, Wk3, biasp);
  k1_qkv<<<1536, 512, 0, stream>>>(x, Wp, biasp, Qs, Ks, Vtok);
  k2a_scores<<<256, 1024, 0, stream>>>(Qs, Ks, attn);
  k2t_transpose<<<8192, 256, 0, stream>>>(Vtok, Vq);
  k2b_pv<<<2048, 512, 0, stream>>>(attn, Vq, yhat);
  k3_out<<<2048, 512, 0, stream>>>(yhat, Wk3, bo, outp);
}

// Round 20
// 296.272 us; speedup vs baseline: 1.0983x; 1.0253x over previous
//
#include <hip/hip_runtime.h>
#include <hip/hip_bf16.h>

// MultiheadAttention_ViTNO: B=8, P=256, S=8x8(=64), D=256, NHEAD=8, DK=32, SCALE=64
// R20: R17 base (298us best; R19's counted-vmcnt k2a was neutral -> reverted).
// ONE change: k1's LDS double buffer removed. The pipeline LOAD(u)->regs /
// COMPUTE(u-1) reads LDS / barrier / CVTWRITE(u)->LDS / barrier never needs
// two buffers (sreg holds tile u during compute of u-1). 64KB->32KB LDS
// lifts k1 from 2 to 4 blocks/CU (occupancy 40%->~80%) with an identical
// per-block instruction stream. k0/k2a(grid256 dbuf)/k2t/k2b/k3 = R17 verbatim.

typedef __bf16 bf16;
typedef __attribute__((ext_vector_type(8))) __bf16 bf16x8;
typedef __attribute__((ext_vector_type(4))) float floatx4;
typedef __attribute__((ext_vector_type(8))) unsigned short ushort8;

#define CDIM 2048             // 64*32 flattened (sxy, dk) per head

static __device__ __forceinline__ floatx4 mfma16(bf16x8 a, bf16x8 b, floatx4 c) {
  return __builtin_amdgcn_mfma_f32_16x16x32_bf16(a, b, c, 0, 0, 0);
}

static __device__ __forceinline__ void gload_lds16(const void* g, void* l) {
  __builtin_amdgcn_global_load_lds((const __attribute__((address_space(1))) void*)g,
                                   (__attribute__((address_space(3))) void*)l, 16, 0, 0);
}

// ---------------- K0: weight prep (R17 verbatim) ----------------
__global__ __launch_bounds__(256) void k0_prep(
    const float* __restrict__ Wq, const float* __restrict__ bq,
    const float* __restrict__ Wk, const float* __restrict__ bk,
    const float* __restrict__ Wv, const float* __restrict__ bv,
    const float* __restrict__ Wo,
    bf16* __restrict__ Wp, bf16* __restrict__ Wk3, float* __restrict__ biasp)
{
  const int bid = blockIdx.x, tid = threadIdx.x;
  int g = (bid & 31) * 256 + tid;       // 0..8191 : (kk, rowblk, lane)
  int lane = g & 63, rowblk = (g >> 6) & 15, kk = g >> 10;
  int h = lane >> 4, cl = lane & 15;
  int d0 = kk * 32 + 8 * h;
  if (bid < 32) {
    int ip = rowblk * 16 + cl;          // i' = n*32+dk
    int isrc = ((ip & 31) << 3) | (ip >> 5);
#pragma unroll
    for (int mat = 0; mat < 3; mat++) {
      const float* W = (mat == 0) ? Wq : (mat == 1) ? Wk : Wv;
      bf16x8 v;
#pragma unroll
      for (int j = 0; j < 8; j++) v[j] = (bf16)W[isrc * 256 + d0 + j];
      *reinterpret_cast<bf16x8*>(Wp + ((size_t)mat * 8192 + g) * 8) = v;
    }
    if (bid == 0 && tid < 256) {
      int bs = ((tid & 31) << 3) | (tid >> 5);
      biasp[tid] = bq[bs]; biasp[256 + tid] = bk[bs]; biasp[512 + tid] = bv[bs];
    }
  } else {
    int j = rowblk * 16 + cl;           // output col
    bf16x8 v;
#pragma unroll
    for (int jj = 0; jj < 8; jj++) {
      int c = d0 + jj;
      v[jj] = (bf16)Wo[j * 256 + (((c & 31) << 3) | (c >> 5))];
    }
    *reinterpret_cast<bf16x8*>(Wk3 + (size_t)g * 8) = v;
  }
}

// ---------------- K1: fused QKV projection, single-buffer pipeline ----------
// grid 1536; block 512 (8 waves); 4 units/block, vb = bx + 1536*u.
// LOAD(u)->sreg || COMPUTE(u-1) reads LDS; barrier; CVTWRITE(u)->LDS; barrier.
// One 32KB buffer -> 4 blocks/CU (was 2 with the redundant double buffer).
__global__ __launch_bounds__(512, 4) void k1_qkv(
    const float* __restrict__ x, const bf16* __restrict__ Wp,
    const float* __restrict__ biasp,
    bf16* __restrict__ Qs, bf16* __restrict__ Ks, bf16* __restrict__ Vt)
{
  __shared__ bf16 buf[64 * 256];        // 32KB, granule-XOR-swizzled
  const int bx = blockIdx.x;
  const int tid = threadIdx.x;
  const int lane = tid & 63;
  const int w = tid >> 6;               // wave 0..7 -> ip slice [w*32, w*32+32)
  const int h = lane >> 4, cl = lane & 15;
  const int c7 = cl & 7;

  floatx4 sreg[8];                      // 32 VGPR staging (one 64-token tile)

#define K1_LOAD(VB)                                                          \
  {                                                                          \
    int a_ = (VB) / 24;                                                      \
    int t0_ = (a_ * 8 + ((VB) & 7)) * 64;                                    \
    _Pragma("unroll")                                                        \
    for (int k = 0; k < 4; ++k) {                                            \
      int G = k * 512 + tid;                                                 \
      int row = G >> 5;                                                      \
      const float* sp = x + (size_t)(t0_ + row) * 256 + (G & 31) * 8;        \
      sreg[2 * k]     = *reinterpret_cast<const floatx4*>(sp);               \
      sreg[2 * k + 1] = *reinterpret_cast<const floatx4*>(sp + 4);           \
    }                                                                        \
  }

#define K1_CVTWRITE()                                                        \
  {                                                                          \
    _Pragma("unroll")                                                        \
    for (int k = 0; k < 4; ++k) {                                            \
      int G = k * 512 + tid;                                                 \
      int row = G >> 5;                                                      \
      bf16x8 v;                                                              \
      _Pragma("unroll")                                                      \
      for (int j = 0; j < 4; j++) {                                          \
        v[j] = (bf16)sreg[2 * k][j];                                         \
        v[4 + j] = (bf16)sreg[2 * k + 1][j];                                 \
      }                                                                      \
      int Gp = (G & ~7) | ((G ^ row) & 7);                                   \
      *reinterpret_cast<bf16x8*>(&buf[Gp * 8]) = v;                          \
    }                                                                        \
  }

#define K1_COMPUTE(VB)                                                       \
  {                                                                          \
    int a_ = (VB) / 24;                                                      \
    int rem_ = (VB) - a_ * 24;                                               \
    int mat_ = rem_ >> 3;                                                    \
    int t0_ = (a_ * 8 + (rem_ & 7)) * 64;                                    \
    const bf16* Wm = Wp + (size_t)mat_ * 65536;                              \
    floatx4 acc[4][2];                                                       \
    _Pragma("unroll")                                                        \
    for (int i = 0; i < 4; i++)                                              \
      _Pragma("unroll")                                                      \
      for (int j = 0; j < 2; j++) acc[i][j] = (floatx4)0.0f;                 \
    _Pragma("unroll 2")                                                      \
    for (int kk = 0; kk < 8; ++kk) {                                         \
      bf16x8 av[4];                                                          \
      _Pragma("unroll")                                                      \
      for (int mt = 0; mt < 4; mt++) {                                       \
        int rr = mt * 16 + cl;                                               \
        int G = rr * 32 + kk * 4 + h;                                        \
        int Gp = (G & ~7) | ((G ^ c7) & 7);                                  \
        av[mt] = *reinterpret_cast<const bf16x8*>(&buf[Gp * 8]);             \
      }                                                                      \
      bf16x8 b0 = *reinterpret_cast<const bf16x8*>(                          \
          Wm + ((size_t)(kk * 16 + w * 2 + 0) * 64 + lane) * 8);             \
      bf16x8 b1 = *reinterpret_cast<const bf16x8*>(                          \
          Wm + ((size_t)(kk * 16 + w * 2 + 1) * 64 + lane) * 8);             \
      _Pragma("unroll")                                                      \
      for (int mt = 0; mt < 4; mt++) acc[mt][0] = mfma16(av[mt], b0, acc[mt][0]); \
      _Pragma("unroll")                                                      \
      for (int mt = 0; mt < 4; mt++) acc[mt][1] = mfma16(av[mt], b1, acc[mt][1]); \
    }                                                                        \
    int b_ = t0_ >> 14;                                                      \
    int p_ = (t0_ >> 6) & 255;                                               \
    if (mat_ < 2) {                                                          \
      bf16* ob = ((mat_ == 0) ? Qs : Ks) + ((size_t)(b_ * 8 + w) * 256 + p_) * 2048; \
      _Pragma("unroll")                                                      \
      for (int nt = 0; nt < 2; nt++) {                                       \
        const int ip = w * 32 + nt * 16 + cl;                                \
        const float bb = biasp[mat_ * 256 + ip];                             \
        const int dk = nt * 16 + cl;                                         \
        _Pragma("unroll")                                                    \
        for (int mt = 0; mt < 4; mt++)                                       \
          _Pragma("unroll")                                                  \
          for (int r = 0; r < 4; r++) {                                      \
            int sxy = mt * 16 + 4 * h + r;                                   \
            ob[sxy * 32 + dk] = (bf16)(acc[mt][nt][r] + bb);                 \
          }                                                                  \
      }                                                                      \
    } else {                                                                 \
      _Pragma("unroll")                                                      \
      for (int nt = 0; nt < 2; nt++) {                                       \
        const int ip = w * 32 + nt * 16 + cl;                                \
        const float bb = biasp[512 + ip];                                    \
        _Pragma("unroll")                                                    \
        for (int mt = 0; mt < 4; mt++)                                       \
          _Pragma("unroll")                                                  \
          for (int r = 0; r < 4; r++) {                                      \
            int t = t0_ + mt * 16 + 4 * h + r;                               \
            Vt[(size_t)t * 256 + ip] = (bf16)(acc[mt][nt][r] + bb);          \
          }                                                                  \
      }                                                                      \
    }                                                                        \
  }

  K1_LOAD(bx);
  K1_CVTWRITE();
  __syncthreads();
#pragma unroll
  for (int u = 1; u < 4; ++u) {
    K1_LOAD(bx + u * 1536);
    K1_COMPUTE(bx + (u - 1) * 1536);
    __syncthreads();                    // tile u-1 reads complete
    K1_CVTWRITE();                      // publish tile u
    __syncthreads();
  }
  K1_COMPUTE(bx + 3 * 1536);

#undef K1_LOAD
#undef K1_CVTWRITE
#undef K1_COMPUTE
}

// ---------------- K2a: scores + softmax (grid 256, R17 verbatim) ----------------
__global__ __launch_bounds__(1024, 1) void k2a_scores(
    const bf16* __restrict__ Qs, const bf16* __restrict__ Ks,
    bf16* __restrict__ attn)
{
  __shared__ bf16 Qch[2][64 * 64];      // 8KB x2
  __shared__ bf16 Kch[2][256 * 64];     // 32KB x2  (80KB total)
  __shared__ float redmax[4][4][16];
  __shared__ float redsum[4][4][16];

  const int bx = blockIdx.x;
  const int bn = bx & 63;
  const int p0 = (bx >> 6) * 64;
  const int tid = threadIdx.x;
  const int lane = tid & 63;
  const int w = tid >> 6;               // 0..15
  const int wr = w >> 2, wc = w & 3;
  const int h = lane >> 4, cl = lane & 15;

  const bf16* Qb = Qs + (size_t)bn * 524288 + (size_t)p0 * 2048;
  const bf16* Kb = Ks + (size_t)bn * 524288;

  const int rq = tid >> 3, sq = (tid & 7) ^ (rq & 7);
  const size_t qsrc = (size_t)rq * 2048 + sq * 8;
  int rk[2]; size_t ksrc[2];
#pragma unroll
  for (int i = 0; i < 2; ++i) {
    int L = i * 1024 + tid;
    rk[i] = L >> 3;
    int s = (L & 7) ^ (rk[i] & 7);
    ksrc[i] = (size_t)rk[i] * 2048 + s * 8;
  }

#define K2A_STAGE(bufi, c)                                                  \
  {                                                                         \
    if (tid < 512) gload_lds16(Qb + qsrc + (c) * 64, &Qch[bufi][(w * 64) * 8]); \
    gload_lds16(Kb + ksrc[0] + (c) * 64, &Kch[bufi][(w * 64) * 8]);         \
    gload_lds16(Kb + ksrc[1] + (c) * 64, &Kch[bufi][(1024 + w * 64) * 8]);  \
  }

  floatx4 acc[4];                       // [nt]; wave rows = wr*16 + 4h + r
#pragma unroll
  for (int j = 0; j < 4; j++) acc[j] = (floatx4)0.0f;

  K2A_STAGE(0, 0);
  __syncthreads();
  int buf = 0;
  for (int c = 0; c < 32; ++c) {
    if (c + 1 < 32) K2A_STAGE(buf ^ 1, c + 1);
#pragma unroll
    for (int kk = 0; kk < 2; ++kk) {
      bf16x8 av, bv[4];
      {
        int row = wr * 16 + cl;
        int gg = kk * 4 + h;
        av = *reinterpret_cast<const bf16x8*>(
            &Qch[buf][(row * 8 + (gg ^ (row & 7))) * 8]);
      }
#pragma unroll
      for (int nt = 0; nt < 4; nt++) {
        int row = wc * 64 + nt * 16 + cl;
        int gg = kk * 4 + h;
        bv[nt] = *reinterpret_cast<const bf16x8*>(
            &Kch[buf][(row * 8 + (gg ^ (row & 7))) * 8]);
      }
#pragma unroll
      for (int nt = 0; nt < 4; nt++) acc[nt] = mfma16(av, bv[nt], acc[nt]);
    }
    __syncthreads();
    buf ^= 1;
  }

  float pm[4];
#pragma unroll
  for (int r = 0; r < 4; r++)
    pm[r] = fmaxf(fmaxf(acc[0][r], acc[1][r]), fmaxf(acc[2][r], acc[3][r]));
#pragma unroll
  for (int off = 1; off < 16; off <<= 1)
#pragma unroll
    for (int r = 0; r < 4; r++)
      pm[r] = fmaxf(pm[r], __shfl_xor(pm[r], off, 64));
  if (cl == 0) {
#pragma unroll
    for (int r = 0; r < 4; r++) redmax[wr][wc][4 * h + r] = pm[r];
  }
  __syncthreads();

  float gm[4], ps[4];
#pragma unroll
  for (int r = 0; r < 4; r++) {
    int row = 4 * h + r;
    gm[r] = fmaxf(fmaxf(redmax[wr][0][row], redmax[wr][1][row]),
                  fmaxf(redmax[wr][2][row], redmax[wr][3][row]));
    ps[r] = 0.0f;
  }
  const float KS = 1.44269504088896340736f / 64.0f;   // log2(e)/SCALE
#pragma unroll
  for (int nt = 0; nt < 4; nt++)
#pragma unroll
    for (int r = 0; r < 4; r++) {
      float e = exp2f((acc[nt][r] - gm[r]) * KS);
      acc[nt][r] = e;
      ps[r] += e;
    }
#pragma unroll
  for (int off = 1; off < 16; off <<= 1)
#pragma unroll
    for (int r = 0; r < 4; r++) ps[r] += __shfl_xor(ps[r], off, 64);
  if (cl == 0) {
#pragma unroll
    for (int r = 0; r < 4; r++) redsum[wr][wc][4 * h + r] = ps[r];
  }
  __syncthreads();

#pragma unroll
  for (int r = 0; r < 4; r++) {
    int row = 4 * h + r;
    float gs = (redsum[wr][0][row] + redsum[wr][1][row])
             + (redsum[wr][2][row] + redsum[wr][3][row]);
    ps[r] = 1.0f / gs;
  }
#pragma unroll
  for (int nt = 0; nt < 4; nt++) {
    int q = wc * 64 + nt * 16 + cl;
#pragma unroll
    for (int r = 0; r < 4; r++) {
      int row = p0 + wr * 16 + 4 * h + r;
      attn[(size_t)bn * 65536 + row * 256 + q] = (bf16)(acc[nt][r] * ps[r]);
    }
  }
#undef K2A_STAGE
}

// ---------------- K2t: V transpose (R17 verbatim) ----------------
__global__ __launch_bounds__(256) void k2t_transpose(
    const bf16* __restrict__ Vtok, bf16* __restrict__ Vq)
{
  const int bx = blockIdx.x;
  const int bn = bx & 63;
  const int r2 = bx >> 6;                  // 0..127
  const int q0 = (r2 & 3) * 64;
  const int c0 = (r2 >> 2) * 64;           // c = sxy*32 + dk
  const int b = bn >> 3, n = bn & 7;
  __shared__ unsigned short tile[64][65];
  const unsigned short* src = (const unsigned short*)Vtok;
  unsigned short* dst = (unsigned short*)Vq + (size_t)bn * 524288;
  {
    const int q = threadIdx.x >> 3;            // 0..31
    const int cj = (threadIdx.x & 7) * 8;
    const int c = c0 + cj;
    const int sxy = c >> 5, dk0 = c & 31;
#pragma unroll
    for (int it = 0; it < 2; ++it) {
      int qq = q + it * 32;
      size_t sa = (size_t)((b * 256 + q0 + qq) * 64 + sxy) * 256 + n * 32 + dk0;
      ushort8 s = *reinterpret_cast<const ushort8*>(src + sa);
#pragma unroll
      for (int j = 0; j < 8; j++) tile[qq][cj + j] = s[j];
    }
  }
  __syncthreads();
  {
    const int crow = threadIdx.x >> 2;         // 0..63
    const int qj = (threadIdx.x & 3) * 8;
#pragma unroll
    for (int it = 0; it < 2; ++it) {
      int qq = qj + it * 32;
      ushort8 sv;
#pragma unroll
      for (int j = 0; j < 8; j++) sv[j] = tile[qq + j][crow];
      *reinterpret_cast<ushort8*>(dst + (size_t)(c0 + crow) * 256 + q0 + qq) = sv;
    }
  }
}

// ---------------- K2b: O = attn @ V (R17 verbatim) ----------------
__global__ __launch_bounds__(512, 6) void k2b_pv(
    const bf16* __restrict__ attn, const bf16* __restrict__ Vq,
    bf16* __restrict__ yhat)
{
  __shared__ bf16 As[64 * 256];         // 32KB
  const int bx = blockIdx.x;
  const int bn = bx & 63;
  const int r2 = bx >> 6;               // 0..31
  const int p0 = (r2 & 3) * 64;
  const int c0 = (r2 >> 2) * 256;
  const int b = bn >> 3, n = bn & 7;
  const int tid = threadIdx.x;
  const int lane = tid & 63;
  const int w = tid >> 6;               // wave -> 32-c slice of ctile
  const int h = lane >> 4, cl = lane & 15;
  const int c7 = cl & 7;

  const bf16* Ab = attn + (size_t)bn * 65536 + (size_t)p0 * 256;
  const bf16* Vb = Vq + (size_t)bn * 524288;

#pragma unroll
  for (int i = 0; i < 4; ++i) {
    int L = (i * 8 + w) * 64 + lane;
    int S = (L & ~7) | ((L ^ (L >> 5)) & 7);
    gload_lds16(Ab + (size_t)S * 8, &As[(size_t)(i * 8 + w) * 64 * 8]);
  }
  __syncthreads();

  floatx4 acc[4][2];
#pragma unroll
  for (int i = 0; i < 4; i++)
#pragma unroll
    for (int j = 0; j < 2; j++) acc[i][j] = (floatx4)0.0f;

#pragma unroll 2
  for (int kk = 0; kk < 8; ++kk) {
    bf16x8 av[4];
#pragma unroll
    for (int mt = 0; mt < 4; mt++) {
      int rr = mt * 16 + cl;
      int G = rr * 32 + kk * 4 + h;
      int Gp = (G & ~7) | ((G ^ c7) & 7);
      av[mt] = *reinterpret_cast<const bf16x8*>(&As[Gp * 8]);
    }
    bf16x8 b0 = *reinterpret_cast<const bf16x8*>(
        Vb + (size_t)(c0 + w * 32 + cl) * 256 + kk * 32 + 8 * h);
    bf16x8 b1 = *reinterpret_cast<const bf16x8*>(
        Vb + (size_t)(c0 + w * 32 + 16 + cl) * 256 + kk * 32 + 8 * h);
#pragma unroll
    for (int mt = 0; mt < 4; mt++) acc[mt][0] = mfma16(av[mt], b0, acc[mt][0]);
#pragma unroll
    for (int mt = 0; mt < 4; mt++) acc[mt][1] = mfma16(av[mt], b1, acc[mt][1]);
  }

#pragma unroll
  for (int nt = 0; nt < 2; nt++) {
    const int cg = c0 + w * 32 + nt * 16 + cl;
    const int dk = cg & 31, sxy = cg >> 5;
#pragma unroll
    for (int mt = 0; mt < 4; mt++)
#pragma unroll
      for (int r = 0; r < 4; r++) {
        int p = p0 + mt * 16 + 4 * h + r;
        size_t t = (size_t)((b * 256 + p) * 64) + sxy;
        yhat[t * 256 + n * 32 + dk] = (bf16)acc[mt][nt][r];
      }
  }
}

// ---------------- K3: output projection (R17 verbatim) ----------------
__global__ __launch_bounds__(512, 6) void k3_out(
    const bf16* __restrict__ yhat, const bf16* __restrict__ Wk3,
    const float* __restrict__ bo, float* __restrict__ outp)
{
  __shared__ bf16 As[64 * 256];         // 32KB
  const int t0 = blockIdx.x * 64;
  const int tid = threadIdx.x;
  const int lane = tid & 63;
  const int w = tid >> 6;
  const int h = lane >> 4, cl = lane & 15;
  const int c7 = cl & 7;

  const bf16* Ab = yhat + (size_t)t0 * 256;

#pragma unroll
  for (int i = 0; i < 4; ++i) {
    int L = (i * 8 + w) * 64 + lane;
    int S = (L & ~7) | ((L ^ (L >> 5)) & 7);
    gload_lds16(Ab + (size_t)S * 8, &As[(size_t)(i * 8 + w) * 64 * 8]);
  }
  __syncthreads();

  floatx4 acc[4][2];
#pragma unroll
  for (int i = 0; i < 4; i++)
#pragma unroll
    for (int j = 0; j < 2; j++) acc[i][j] = (floatx4)0.0f;

#pragma unroll 2
  for (int kk = 0; kk < 8; ++kk) {
    bf16x8 av[4];
#pragma unroll
    for (int mt = 0; mt < 4; mt++) {
      int rr = mt * 16 + cl;
      int G = rr * 32 + kk * 4 + h;
      int Gp = (G & ~7) | ((G ^ c7) & 7);
      av[mt] = *reinterpret_cast<const bf16x8*>(&As[Gp * 8]);
    }
    bf16x8 b0 = *reinterpret_cast<const bf16x8*>(
        Wk3 + ((size_t)(kk * 16 + w * 2 + 0) * 64 + lane) * 8);
    bf16x8 b1 = *reinterpret_cast<const bf16x8*>(
        Wk3 + ((size_t)(kk * 16 + w * 2 + 1) * 64 + lane) * 8);
#pragma unroll
    for (int mt = 0; mt < 4; mt++) acc[mt][0] = mfma16(av[mt], b0, acc[mt][0]);
#pragma unroll
    for (int mt = 0; mt < 4; mt++) acc[mt][1] = mfma16(av[mt], b1, acc[mt][1]);
  }

#pragma unroll
  for (int nt = 0; nt < 2; nt++) {
    const int j = w * 32 + nt * 16 + cl;
    const float bb = bo[j];
#pragma unroll
    for (int mt = 0; mt < 4; mt++)
#pragma unroll
      for (int r = 0; r < 4; r++)
        outp[(size_t)(t0 + mt * 16 + 4 * h + r) * 256 + j] = acc[mt][nt][r] + bb;
  }
}

// ---------------- launch ----------------
extern "C" void kernel_launch(void* const* d_in, const int* in_sizes, int n_in,
                              void* d_out, int out_size, void* d_ws, size_t ws_size,
                              hipStream_t stream) {
  const float* x  = (const float*)d_in[0];
  const float* Wq = (const float*)d_in[1];
  const float* bq = (const float*)d_in[2];
  const float* Wk = (const float*)d_in[3];
  const float* bk = (const float*)d_in[4];
  const float* Wv = (const float*)d_in[5];
  const float* bv = (const float*)d_in[6];
  const float* Wo = (const float*)d_in[7];
  const float* bo = (const float*)d_in[8];
  float* outp = (float*)d_out;

  char* ws = (char*)d_ws;
  const size_t SZ_QKV = 67108864;   // 64*256*2048 * 2B
  size_t off = 0;
  bf16* Qs   = (bf16*)(ws + off); off += SZ_QKV;
  bf16* Ks   = (bf16*)(ws + off); off += SZ_QKV;
  bf16* Vtok = (bf16*)(ws + off); off += SZ_QKV;
  bf16* attn = (bf16*)(ws + off); off += 8388608;
  bf16* Wp   = (bf16*)(ws + off); off += 393216;   // qkv fragment packs
  bf16* Wk3  = (bf16*)(ws + off); off += 131072;   // k3 fragment pack
  float* biasp = (float*)(ws + off); off += 3072;
  if (ws_size < off) return;        // workspace too small: bail cleanly

  bf16* yhat = Qs;                  // Qs dead after k2a
  bf16* Vq   = Ks;                  // Ks dead after k2a (k2t runs after k2a)

  k0_prep<<<64, 256, 0, stream>>>(Wq, bq, Wk, bk, Wv, bv, Wo, Wp, Wk3, biasp);
  k1_qkv<<<1536, 512, 0, stream>>>(x, Wp, biasp, Qs, Ks, Vtok);
  k2a_scores<<<256, 1024, 0, stream>>>(Qs, Ks, attn);
  k2t_transpose<<<8192, 256, 0, stream>>>(Vtok, Vq);
  k2b_pv<<<2048, 512, 0, stream>>>(attn, Vq, yhat);
  k3_out<<<2048, 512, 0, stream>>>(yhat, Wk3, bo, outp);
}